// Round 1
// baseline (118.012 us; speedup 1.0000x reference)
//
#include <hip/hip_runtime.h>
#include <math.h>

#define EPS 1e-6f
constexpr int B   = 64;
constexpr int F   = 2;
constexpr int NC  = 10;
constexpr int ND  = 4;
constexpr int CHW = 64 * 16 * 16;   // 16384
constexpr int FCHW = F * CHW;       // 32768

__device__ __forceinline__ float log_sigmoid(float x) {
    // jax.nn.log_sigmoid: -log1p(exp(-x)), stabilized
    return fminf(x, 0.0f) - log1pf(expf(-fabsf(x)));
}

// K1: bins[nc][i] = X_LEs[nc][i] + sum_{b: labels[b]==nc} x_LE[b][i]
__global__ void k_bins(const float* __restrict__ xLE, const int* __restrict__ labels,
                       const float* __restrict__ XLEs, float* __restrict__ bins) {
    int i = blockIdx.x * blockDim.x + threadIdx.x;   // [0, FCHW)
    float acc[NC];
#pragma unroll
    for (int nc = 0; nc < NC; ++nc) acc[nc] = 0.0f;
    for (int b = 0; b < B; ++b) {
        int lb  = labels[b];            // wave-uniform scalar load
        float v = xLE[b * FCHW + i];    // coalesced
#pragma unroll
        for (int nc = 0; nc < NC; ++nc)
            acc[nc] += (lb == nc) ? v : 0.0f;
    }
#pragma unroll
    for (int nc = 0; nc < NC; ++nc)
        bins[nc * FCHW + i] = XLEs[nc * FCHW + i] + acc[nc];
}

// K2: per (nc, s): means_theta, log(means_mag+EPS); block-reduced norm[nd][nc]
__global__ void k_means_norm(const float* __restrict__ bins, const int* __restrict__ labels,
                             const float* __restrict__ w1, const float* __restrict__ miu,
                             const float* __restrict__ tao, const float* __restrict__ sigmas,
                             const float* __restrict__ Xw,
                             float* __restrict__ means_theta, float* __restrict__ lnm,
                             float* __restrict__ norm /* [ND][NC] */) {
    int s  = blockIdx.x * blockDim.x + threadIdx.x;  // [0, CHW)
    int nc = blockIdx.y;

    int cint = 0;
    for (int b = 0; b < B; ++b) cint += (labels[b] == nc);
    float cnt = Xw[nc] + (float)cint;
    float inv_cnt = 1.0f / cnt;

    float w1sq[ND];
    float s1 = 0.0f;
#pragma unroll
    for (int nd = 0; nd < ND; ++nd) { float t = w1[nd]; w1sq[nd] = t * t; s1 += t * t; }
    float inv_s1 = 1.0f / s1;
    float sg = sigmas[nc];
    float sig2 = sg * sg;

    float xb0 = bins[nc * FCHW + s] * inv_cnt;
    float xb1 = bins[nc * FCHW + CHW + s] * inv_cnt;
    float ls0  = log_sigmoid(xb0);
    float ls1  = log_sigmoid(xb1);
    float ls1e = log_sigmoid(xb1 + EPS);

    float psum[ND];
    float theta = 0.0f, magm = 0.0f;
#pragma unroll
    for (int nd = 0; nd < ND; ++nd) {
        float m0 = miu[nd * FCHW + s];
        float m1 = miu[nd * FCHW + CHW + s];
        float d0 = ls0 - log_sigmoid(m0);
        float d1 = ls1 - log_sigmoid(m1);
        psum[nd] = d0 * d0 + d1 * d1;

        float tv = tao[nd];
        float tao2 = tv * tv;
        float denom = 1.0f / (sig2 + tao2);
        float rt = tao2 * denom;
        float rs = sig2 * denom;
        float wn = w1sq[nd] * inv_s1;      // w1n == w2n in the reference
        theta += (xb1 * rt + m0 * rs) * wn;
        magm  += expf((rt * ls1e + rs * log_sigmoid(m1 + EPS)) * wn);
    }
    means_theta[nc * CHW + s] = theta;
    lnm[nc * CHW + s] = logf(magm + EPS);

    // block-level reduction of psum
#pragma unroll
    for (int nd = 0; nd < ND; ++nd) {
        float v = psum[nd];
        for (int off = 32; off > 0; off >>= 1)
            v += __shfl_down(v, off, 64);
        psum[nd] = v;
    }
    __shared__ float red[4][ND];
    int lane = threadIdx.x & 63;
    int wv   = threadIdx.x >> 6;
    if (lane == 0) {
#pragma unroll
        for (int nd = 0; nd < ND; ++nd) red[wv][nd] = psum[nd];
    }
    __syncthreads();
    if (threadIdx.x < ND) {
        int nd = threadIdx.x;
        float v = red[0][nd] + red[1][nd] + red[2][nd] + red[3][nd];
        atomicAdd(&norm[nd * NC + nc], v);
    }
}

// K3: loss[nd] = mean_nc term1*(term2+term3)
__global__ void k_loss(const float* __restrict__ norm, const int* __restrict__ labels,
                       const float* __restrict__ Xw,
                       const float* __restrict__ tao, const float* __restrict__ sigmas,
                       float* __restrict__ loss_out) {
    int nd = threadIdx.x;
    if (nd >= ND) return;
    float tv = tao[nd];
    float tao2 = tv * tv;
    float tao4 = tao2 * tao2;
    float acc = 0.0f;
    for (int nc = 0; nc < NC; ++nc) {
        int cint = 0;
        for (int b = 0; b < B; ++b) cint += (labels[b] == nc);
        float cnt = Xw[nc] + (float)cint;
        float sg = sigmas[nc];
        float sig2 = sg * sg;
        float t1 = sig2 / ((tao2 + sig2) * (tao2 + sig2));
        float t2 = sig2 * norm[nd * NC + nc];
        float t3 = 2.0f * (float)CHW * (tao4 - sig2 * sig2) / cnt;
        acc += t1 * (t2 + t3);
    }
    loss_out[nd] = acc / (float)NC;
}

// K4: x_out[b][s] = min_nc w0^2*|x0 - mt[nc][s]| + w1^2*|log(x1) - lnm[nc][s]|
__global__ void k_xout(const float* __restrict__ xLE, const float* __restrict__ means_theta,
                       const float* __restrict__ lnm, const float* __restrict__ weight,
                       float* __restrict__ xout) {
    int idx = blockIdx.x * blockDim.x + threadIdx.x;  // [0, B*CHW)
    int b = idx >> 14;
    int s = idx & (CHW - 1);
    float x0 = xLE[b * FCHW + s];
    float x1 = xLE[b * FCHW + CHW + s];
    float lnx1 = logf(x1);
    float wv0 = weight[0], wv1 = weight[1];
    float w0 = wv0 * wv0, w1s = wv1 * wv1;
    float best = INFINITY;
#pragma unroll
    for (int nc = 0; nc < NC; ++nc) {
        float dr = fabsf(x0 - means_theta[nc * CHW + s]);
        float da = fabsf(lnx1 - lnm[nc * CHW + s]);
        float d = w0 * dr + w1s * da;
        best = fminf(best, d);
    }
    xout[idx] = best;
}

extern "C" void kernel_launch(void* const* d_in, const int* in_sizes, int n_in,
                              void* d_out, int out_size, void* d_ws, size_t ws_size,
                              hipStream_t stream) {
    const float* xLE    = (const float*)d_in[0];
    const int*   labels = (const int*)  d_in[1];
    const float* w1     = (const float*)d_in[2];
    // d_in[3] (w2) is unused: the reference computes w2n from w1.
    const float* miu    = (const float*)d_in[4];
    const float* tao    = (const float*)d_in[5];
    const float* weight = (const float*)d_in[6];
    const float* sigmas = (const float*)d_in[7];
    const float* XLEs   = (const float*)d_in[8];
    const float* Xw     = (const float*)d_in[9];

    float* out = (float*)d_out;               // x_out [B*CHW] then loss [ND]

    float* bins        = (float*)d_ws;        // NC*FCHW = 327680
    float* means_theta = bins + NC * FCHW;    // NC*CHW  = 163840
    float* lnm         = means_theta + NC * CHW; // NC*CHW
    float* norm        = lnm + NC * CHW;      // ND*NC = 40

    hipMemsetAsync(norm, 0, ND * NC * sizeof(float), stream);

    k_bins<<<FCHW / 256, 256, 0, stream>>>(xLE, labels, XLEs, bins);

    k_means_norm<<<dim3(CHW / 256, NC), 256, 0, stream>>>(
        bins, labels, w1, miu, tao, sigmas, Xw, means_theta, lnm, norm);

    k_loss<<<1, 64, 0, stream>>>(norm, labels, Xw, tao, sigmas, out + B * CHW);

    k_xout<<<(B * CHW) / 256, 256, 0, stream>>>(xLE, means_theta, lnm, weight, out);
}